// Round 7
// baseline (1034.723 us; speedup 1.0000x reference)
//
#include <hip/hip_runtime.h>
#include <stdint.h>

// DeepSpeed self-attention forward, bf16-MFMA implementation.
// B=2, S=1024, H=4096, NH=32, HD=128. All matmuls via mfma_f32_16x16x32_bf16.
// Round 8: QKV tile 256x384 (grid 8x32 = 256 = exactly 1 CU pass), per-wave
// 128x96 (acc[8][6]). Per CU-step MFMA 1776 cyc >= LDS 1700 cyc — first
// MFMA-dominant geometry. Uniform 5 stage-ops/wave -> vmcnt(5), 3-buffer
// (120 KB), one barrier/step. Proj/attn/LN/transconv unchanged from round 6.

#define S_LEN 1024
#define HID   4096
#define NHEAD 32
#define HDIM  128

typedef __attribute__((ext_vector_type(8))) short bf16x8;   // 8 bf16 (4 VGPRs)
typedef __attribute__((ext_vector_type(4))) float f32x4;    // MFMA C/D
typedef __attribute__((ext_vector_type(8))) unsigned short us8; // 16B store

__device__ __forceinline__ unsigned short f2bf(float f) {
    union { float f; unsigned u; } v; v.f = f;
    unsigned r = v.u + 0x7fffu + ((v.u >> 16) & 1u);
    return (unsigned short)(r >> 16);
}

__device__ __forceinline__ void gld16(const unsigned short* g, unsigned short* l) {
    __builtin_amdgcn_global_load_lds(
        (const __attribute__((address_space(1))) void*)g,
        (__attribute__((address_space(3))) void*)l, 16, 0, 0);
}

// ---------------- LayerNorm + bf16 cast: x[2048][4096] -> inp_norm bf16 ----------
__global__ __launch_bounds__(256) void ln_kernel(const float* __restrict__ x,
        const float* __restrict__ w, const float* __restrict__ bch,
        unsigned short* __restrict__ out) {
    const int row = blockIdx.x;
    const int t = threadIdx.x;
    const float* xr = x + (size_t)row * HID;
    float4 v[4];
    float sum = 0.f, sq = 0.f;
#pragma unroll
    for (int i = 0; i < 4; i++) {
        v[i] = ((const float4*)xr)[t + (i << 8)];
        sum += v[i].x + v[i].y + v[i].z + v[i].w;
        sq  += v[i].x*v[i].x + v[i].y*v[i].y + v[i].z*v[i].z + v[i].w*v[i].w;
    }
#pragma unroll
    for (int off = 32; off; off >>= 1) {
        sum += __shfl_down(sum, off);
        sq  += __shfl_down(sq, off);
    }
    __shared__ float ssum[4], ssq[4];
    if ((t & 63) == 0) { ssum[t >> 6] = sum; ssq[t >> 6] = sq; }
    __syncthreads();
    const float s_all = ssum[0] + ssum[1] + ssum[2] + ssum[3];
    const float q_all = ssq[0] + ssq[1] + ssq[2] + ssq[3];
    const float mean = s_all * (1.f / HID);
    const float var  = q_all * (1.f / HID) - mean * mean;
    const float rstd = rsqrtf(var + 1e-5f);
    unsigned short* orow = out + (size_t)row * HID;
#pragma unroll
    for (int i = 0; i < 4; i++) {
        float4 wv = ((const float4*)w)[t + (i << 8)];
        float4 bv = ((const float4*)bch)[t + (i << 8)];
        ushort4 o;
        o.x = f2bf((v[i].x - mean) * rstd * wv.x + bv.x);
        o.y = f2bf((v[i].y - mean) * rstd * wv.y + bv.y);
        o.z = f2bf((v[i].z - mean) * rstd * wv.z + bv.z);
        o.w = f2bf((v[i].w - mean) * rstd * wv.w + bv.w);
        ((ushort4*)orow)[t + (i << 8)] = o;
    }
}

// ------------- transpose + fp32->bf16: W[K][N] -> Wt[N][K] ----------------------
__global__ __launch_bounds__(256) void transconv(const float* __restrict__ W,
        unsigned short* __restrict__ Wt, int K, int N) {
    __shared__ float tileT[128 * 65];   // [n][k], pad 65 (33.3 KB)
    const int n0 = blockIdx.x << 7, k0 = blockIdx.y << 6;
    const int t = threadIdx.x;
#pragma unroll
    for (int it = 0; it < 8; it++) {
        int idx = (it << 8) + t;
        int r = idx >> 5;            // k row 0..63
        int c4 = idx & 31;           // float4 column 0..31
        float4 v = *(const float4*)(W + (size_t)(k0 + r) * N + n0 + (c4 << 2));
        tileT[((c4 << 2) + 0) * 65 + r] = v.x;
        tileT[((c4 << 2) + 1) * 65 + r] = v.y;
        tileT[((c4 << 2) + 2) * 65 + r] = v.z;
        tileT[((c4 << 2) + 3) * 65 + r] = v.w;
    }
    __syncthreads();
#pragma unroll
    for (int it = 0; it < 4; it++) {
        int idx = (it << 8) + t;
        int n = idx >> 3;            // 0..127
        int k8 = idx & 7;            // ushort8 column, 0..7 (8 k each)
        const float* src = &tileT[n * 65 + (k8 << 3)];
        us8 o;
#pragma unroll
        for (int e = 0; e < 8; e++) o[e] = f2bf(src[e]);
        *(us8*)(Wt + (size_t)(n0 + n) * K + k0 + (k8 << 3)) = o;
    }
}

// =================================================================================
// QKV GEMM: 256x384 tile, 512 thr = 8 waves (2M x 4N), per-wave 128x96.
// K-step = 32 (128 steps). LDS: 3 rotating bufs x { A[256][32] 16KB + B[384][32]
// 24KB } = 120 KB. One barrier per step:
//   { stage step t+2 -> buf p (A 2 + B 3 gld_lds, uniform per wave) ;
//     14 ds_read_b128 (A 8 + B 3+3 bundled) ; 48 MFMA ; vmcnt(5) ; s_barrier }
// vmcnt(5) forces tile t+1's 5 loads (issued 1 step earlier), leaves tile t+2's
// 5 in flight -> ~2-step (~3500 cyc) latency slack, never vmcnt(0) in loop.
// Single barrier safe (r6-verified): reads of cur complete before own MFMA
// (lgkm), MFMA before barrier; stage targets buf cur-1 whose reads finished
// before the PREVIOUS barrier.
// Per-CU-step budget: MFMA 2x48x18.5 = 1776 cyc >= LDS (112 rd x12 + 40KB wr)
// ~1700 cyc -> first MFMA-dominant tiling. Grid 256 = exactly 1 pass.
// Swizzle (both sides): src col chunk ^= lane-derived; ds_read chunk^((r>>1)&3).
// =================================================================================

#define QK_STEP(TT, CURB, PFB)                                                    \
  {                                                                               \
    int pf_ = (TT) + 2; if (pf_ > 127) pf_ = 127;                                 \
    stgA(pf_, PFB); stgB(pf_, PFB);                                               \
    bf16x8 af[8], bfv[3];                                                         \
    _Pragma("unroll") for (int ii = 0; ii < 8; ii++) af[ii] = ldA(CURB, ii);      \
    _Pragma("unroll") for (int jj = 0; jj < 3; jj++) bfv[jj] = ldB(CURB, jj);     \
    __builtin_amdgcn_s_setprio(1);                                                \
    _Pragma("unroll") for (int jj = 0; jj < 3; jj++)                              \
      _Pragma("unroll") for (int ii = 0; ii < 8; ii++)                            \
        acc[ii][jj] = __builtin_amdgcn_mfma_f32_16x16x32_bf16(                    \
            af[ii], bfv[jj], acc[ii][jj], 0, 0, 0);                               \
    __builtin_amdgcn_s_setprio(0);                                                \
    _Pragma("unroll") for (int jj = 0; jj < 3; jj++) bfv[jj] = ldB(CURB, jj + 3); \
    __builtin_amdgcn_s_setprio(1);                                                \
    _Pragma("unroll") for (int jj = 0; jj < 3; jj++)                              \
      _Pragma("unroll") for (int ii = 0; ii < 8; ii++)                            \
        acc[ii][jj + 3] = __builtin_amdgcn_mfma_f32_16x16x32_bf16(                \
            af[ii], bfv[jj], acc[ii][jj + 3], 0, 0, 0);                           \
    __builtin_amdgcn_s_setprio(0);                                                \
    asm volatile("s_waitcnt vmcnt(5)" ::: "memory");                              \
    __builtin_amdgcn_s_barrier();                                                 \
  }

// Grid 256 = 8 bm x 32 bn = exactly 1 round. bm = orig&7 pins one 2MB A-panel
// per XCD L2; B streams via L3.
__global__ __launch_bounds__(512, 2) void gemm_qkv384(
        const unsigned short* __restrict__ A,
        const unsigned short* __restrict__ Bt,
        const float* __restrict__ bias,
        unsigned short* __restrict__ qb,
        unsigned short* __restrict__ kb,
        unsigned short* __restrict__ vt) {
    __shared__ unsigned short lds[61440];   // 120 KB
    const int orig = blockIdx.x;
    const int bm = orig & 7, bn = orig >> 3;      // bn 0..31
    const int t = threadIdx.x;
    const int wave = t >> 6, lane = t & 63, quad = lane >> 4, l16 = lane & 15;
    const int waveM = wave >> 2, waveN = wave & 3;

    const unsigned short* GA = A  + ((size_t)bm << 8) * HID;   // 256 rows
    const unsigned short* GB = Bt + ((size_t)bn * 384) * HID;  // 384 rows

    const int swz  = (((lane & 3) ^ ((lane >> 3) & 3)) << 3);  // src col (el)
    const int arow = lane >> 2;                                // 0..15 in granule

    // A [256][32]: 16 granules (16 rows x 32 el = 1KB), 2 per wave.
    auto stgA = [&](int tt, int buf) {
#pragma unroll
        for (int u = 0; u < 2; u++) {
            const int g = (wave << 1) + u;                     // 0..15
            gld16(GA + (size_t)((g << 4) + arow) * HID + (tt << 5) + swz,
                  lds + buf * 20480 + (g << 9));
        }
    };
    // B [384][32]: 24 granules, 3 per wave (uniform).
    auto stgB = [&](int tt, int buf) {
#pragma unroll
        for (int u = 0; u < 3; u++) {
            const int g = wave * 3 + u;                        // 0..23
            gld16(GB + (size_t)((g << 4) + arow) * HID + (tt << 5) + swz,
                  lds + buf * 20480 + 8192 + (g << 9));
        }
    };
    auto ldA = [&](int buf, int i) -> bf16x8 {
        const int r = (waveM << 7) + (i << 4) + l16;           // 0..255
        return ((const bf16x8*)lds)
            [buf * 2560 + (r << 2) + (quad ^ ((r >> 1) & 3))];
    };
    auto ldB = [&](int buf, int j) -> bf16x8 {
        const int r = waveN * 96 + (j << 4) + l16;             // 0..383
        return ((const bf16x8*)lds)
            [buf * 2560 + 1024 + (r << 2) + (quad ^ ((r >> 1) & 3))];
    };

    const f32x4 fz = {0.f, 0.f, 0.f, 0.f};
    f32x4 acc[8][6];
#pragma unroll
    for (int i = 0; i < 8; i++)
#pragma unroll
        for (int j = 0; j < 6; j++) acc[i][j] = fz;

    // prologue: step0 -> buf0, step1 -> buf1 (10 vm-ops); force step0's 5.
    stgA(0, 0); stgB(0, 0);
    stgA(1, 1); stgB(1, 1);
    asm volatile("s_waitcnt vmcnt(5)" ::: "memory");
    __builtin_amdgcn_s_barrier();

    for (int tt = 0; tt < 126; tt += 3) {
        QK_STEP(tt,     0, 2)
        QK_STEP(tt + 1, 1, 0)
        QK_STEP(tt + 2, 2, 1)
    }
    QK_STEP(126, 0, 2)
    QK_STEP(127, 1, 0)
    asm volatile("s_waitcnt vmcnt(0)" ::: "memory");   // drain dummy prefetches

    // epilogue: scatter with bias. Tiles straddle the q/k/v boundary; `which`
    // is computed per element (n>>12).
#pragma unroll
    for (int ii = 0; ii < 8; ii++) {
#pragma unroll
        for (int jj = 0; jj < 6; jj++) {
#pragma unroll
            for (int r = 0; r < 4; r++) {
                int m = (bm << 8) + (waveM << 7) + (ii << 4) + (quad << 2) + r;
                int n = bn * 384 + waveN * 96 + (jj << 4) + l16;
                float v = acc[ii][jj][r] + bias[n];
                unsigned short bvv = f2bf(v);
                int bb = m >> 10, s = m & 1023;
                int which = n >> 12;           // 0=q 1=k 2=v
                int h = n & 4095, head = h >> 7, hd = h & 127;
                size_t bh = (size_t)(bb << 5) + head;
                if (which == 0)      qb[(bh * S_LEN + s) * HDIM + hd] = bvv;
                else if (which == 1) kb[(bh * S_LEN + s) * HDIM + hd] = bvv;
                else                 vt[(bh * HDIM + hd) * S_LEN + s] = bvv;
            }
        }
    }
}

// =================================================================================
// Proj GEMM: 256x128 tile, 8 waves (4M x 2N), per-wave 64x64. 1-barrier BK=32
// 3-buffer core; uniform 3 stage-ops/wave -> vmcnt(3). Grid 256 = 1 round.
// =================================================================================

#define PJ_TILE(TT, CURB, PFB)                                                    \
  {                                                                               \
    int pf_ = (TT) + 2; if (pf_ > 127) pf_ = 127;                                 \
    stgA(pf_, PFB); stgB(pf_, PFB);                                               \
    bf16x8 bfv[4], af[4];                                                         \
    _Pragma("unroll") for (int jj = 0; jj < 4; jj++) bfv[jj] = ldB(CURB, jj);     \
    _Pragma("unroll") for (int ii = 0; ii < 4; ii++) af[ii] = ldA(CURB, ii);      \
    __builtin_amdgcn_s_setprio(1);                                                \
    _Pragma("unroll") for (int ii = 0; ii < 4; ii++)                              \
      _Pragma("unroll") for (int jj = 0; jj < 4; jj++)                            \
        acc[ii][jj] = __builtin_amdgcn_mfma_f32_16x16x32_bf16(                    \
            af[ii], bfv[jj], acc[ii][jj], 0, 0, 0);                               \
    __builtin_amdgcn_s_setprio(0);                                                \
    asm volatile("s_waitcnt vmcnt(3)" ::: "memory");                              \
    __builtin_amdgcn_s_barrier();                                                 \
  }

__global__ __launch_bounds__(512, 2) void gemm_proj32(
        const unsigned short* __restrict__ A,
        const unsigned short* __restrict__ Bt,
        float* __restrict__ outf) {
    __shared__ unsigned short lds[36864];   // 72 KB
    const int orig = blockIdx.x;
    const int bm = orig & 7, bn = orig >> 3;      // bn 0..31
    const int t = threadIdx.x;
    const int wave = t >> 6, lane = t & 63, quad = lane >> 4, l16 = lane & 15;
    const int waveM = wave >> 1, waveN = wave & 1;

    const unsigned short* GA = A  + ((size_t)bm << 8) * HID;   // 256 rows
    const unsigned short* GB = Bt + ((size_t)bn << 7) * HID;   // 128 rows

    const int swz  = (((lane & 3) ^ ((lane >> 3) & 3)) << 3);
    const int arow = lane >> 2;

    auto stgA = [&](int tt, int buf) {
#pragma unroll
        for (int u = 0; u < 2; u++) {
            const int g = (wave << 1) + u;                     // 0..15
            gld16(GA + (size_t)((g << 4) + arow) * HID + (tt << 5) + swz,
                  lds + buf * 12288 + (g << 9));
        }
    };
    auto stgB = [&](int tt, int buf) {
        const int g = wave;                                    // 0..7
        gld16(GB + (size_t)((g << 4) + arow) * HID + (tt << 5) + swz,
              lds + buf * 12288 + 8192 + (g << 9));
    };
    auto ldA = [&](int buf, int i) -> bf16x8 {
        const int r = (waveM << 6) + (i << 4) + l16;           // 0..255
        return ((const bf16x8*)lds)
            [((buf * 12288) >> 3) + (r << 2) + (quad ^ ((r >> 1) & 3))];
    };
    auto ldB = [&](int buf, int j) -> bf16x8 {
        const int r = (waveN << 6) + (j << 4) + l16;           // 0..127
        return ((const bf16x8*)lds)
            [((buf * 12288 + 8192) >> 3) + (r << 2) + (quad ^ ((r >> 1) & 3))];
    };

    const f32x4 fz = {0.f, 0.f, 0.f, 0.f};
    f32x4 acc[4][4];
#pragma unroll
    for (int i = 0; i < 4; i++)
#pragma unroll
        for (int j = 0; j < 4; j++) acc[i][j] = fz;

    stgA(0, 0); stgB(0, 0);
    stgA(1, 1); stgB(1, 1);
    asm volatile("s_waitcnt vmcnt(3)" ::: "memory");
    __builtin_amdgcn_s_barrier();

    for (int tt = 0; tt < 126; tt += 3) {
        PJ_TILE(tt,     0, 2)
        PJ_TILE(tt + 1, 1, 0)
        PJ_TILE(tt + 2, 2, 1)
    }
    PJ_TILE(126, 0, 2)
    PJ_TILE(127, 1, 0)
    asm volatile("s_waitcnt vmcnt(0)" ::: "memory");

#pragma unroll
    for (int ii = 0; ii < 4; ii++)
#pragma unroll
        for (int jj = 0; jj < 4; jj++)
#pragma unroll
            for (int r = 0; r < 4; r++) {
                int m = (bm << 8) + (waveM << 6) + (ii << 4) + (quad << 2) + r;
                int n = (bn << 7) + (waveN << 6) + (jj << 4) + l16;
                outf[((size_t)m << 12) + n] = acc[ii][jj][r];
            }
}

// ---------------- flash attention: 64-query tile per block, causal ---------------
// Chunk-XOR swizzle on q/k/v (pre-swizzled global src, gld_lds dest linear) and
// p (swizzled VALU writes); matching XOR on every ds_read.
__global__ __launch_bounds__(256) void attn_kernel(
        const unsigned short* __restrict__ qbuf,   // [64][1024][128]
        const unsigned short* __restrict__ kbuf,   // [64][1024][128]
        const unsigned short* __restrict__ vtbuf,  // [64][128][1024]
        const float* __restrict__ mask,            // [2][1024]
        unsigned short* __restrict__ ctx) {        // [2048][4096]
    __shared__ unsigned short q_lds[64 * 128];
    __shared__ unsigned short k_lds[64 * 128];
    __shared__ unsigned short v_lds[128 * 64];     // [hd][key]
    __shared__ unsigned short p_lds[64 * 64];
    const int t = threadIdx.x;
    const int wave = t >> 6, lane = t & 63, quad = lane >> 4, l16 = lane & 15;
    const int bq = blockIdx.x, bh = blockIdx.y;
    const int q0 = bq << 6;
    const int b = bh >> 5;
    const unsigned short* Q  = qbuf  + (size_t)bh * S_LEN * HDIM;
    const unsigned short* Kp = kbuf  + (size_t)bh * S_LEN * HDIM;
    const unsigned short* Vp = vtbuf + (size_t)bh * HDIM * S_LEN;

    {   // stage Q tile (64x128), src chunk pre-swizzled with row&7
        int r = t >> 4;
        int c = (((t & 15) ^ ((t >> 4) & 7)) << 3);
#pragma unroll
        for (int it = 0; it < 4; it++)
            gld16(Q + (size_t)(q0 + r + (it << 4)) * HDIM + c,
                  q_lds + ((((it << 8) + (wave << 6))) << 3));
    }

    const f32x4 fz = {0.f, 0.f, 0.f, 0.f};
    f32x4 o[8];
#pragma unroll
    for (int n = 0; n < 8; n++) o[n] = fz;
    float l_i[4] = {0.f, 0.f, 0.f, 0.f};
    const float scale = 0.08838834764831845f;   // 1/sqrt(128)
    const float* mrow = mask + b * S_LEN;

    for (int kt = 0; kt <= bq; kt++) {
        const int k0 = kt << 6;
        {   // stage K (64x128) and V^T (128x64), pre-swizzled src
            int rk = t >> 4, ck = (((t & 15) ^ ((t >> 4) & 7)) << 3);
            int rv = t >> 3, cv = (((t & 7) ^ ((t >> 3) & 7)) << 3);
#pragma unroll
            for (int it = 0; it < 4; it++) {
                gld16(Kp + (size_t)(k0 + rk + (it << 4)) * HDIM + ck,
                      k_lds + (((it << 8) + (wave << 6)) << 3));
                gld16(Vp + (size_t)(rv + (it << 5)) * S_LEN + k0 + cv,
                      v_lds + (((it << 8) + (wave << 6)) << 3));
            }
        }
        __syncthreads();

        // QK^T: wave handles 16-query strip, 4 key n-tiles
        f32x4 sacc[4];
#pragma unroll
        for (int j = 0; j < 4; j++) sacc[j] = fz;
        const bf16x8* qv = (const bf16x8*)q_lds;
        const bf16x8* kv = (const bf16x8*)k_lds;
#pragma unroll
        for (int kk = 0; kk < 4; kk++) {
            bf16x8 aq = qv[(((wave << 4) + l16) << 4) + (((kk << 2) + quad) ^ (l16 & 7))];
#pragma unroll
            for (int j = 0; j < 4; j++) {
                bf16x8 bk = kv[((((j << 4) + l16)) << 4) + (((kk << 2) + quad) ^ (l16 & 7))];
                sacc[j] = __builtin_amdgcn_mfma_f32_16x16x32_bf16(aq, bk, sacc[j], 0, 0, 0);
            }
        }

        // softmax numerator: p = exp(score); accumulate row-sum per lane
#pragma unroll
        for (int r = 0; r < 4; r++) {
            int prow = (wave << 4) + (quad << 2) + r;
            int qrow = q0 + prow;
#pragma unroll
            for (int j = 0; j < 4; j++) {
                int key = k0 + (j << 4) + l16;
                float x = sacc[j][r] * scale + mrow[key];
                if (key > qrow) x -= 10000.0f;    // causal: exp underflows to 0
                float p = __expf(x);
                l_i[r] += p;
                int pc = (j << 1) + (l16 >> 3);               // chunk 0..7
                p_lds[(prow << 6) + ((pc ^ (prow & 7)) << 3) + (l16 & 7)] = f2bf(p);
            }
        }
        __syncthreads();

        // PV: O[16 x 128] += P[16 x 64] * V[64 x 128]
        const bf16x8* pvv = (const bf16x8*)p_lds;
        const bf16x8* vv = (const bf16x8*)v_lds;
#pragma unroll
        for (int ks = 0; ks < 2; ks++) {
            bf16x8 ap = pvv[(((wave << 4) + l16) << 3) + (((ks << 2) + quad) ^ (l16 & 7))];
#pragma unroll
            for (int n = 0; n < 8; n++) {
                bf16x8 bvv = vv[((((n << 4) + l16)) << 3) + (((ks << 2) + quad) ^ (l16 & 7))];
                o[n] = __builtin_amdgcn_mfma_f32_16x16x32_bf16(ap, bvv, o[n], 0, 0, 0);
            }
        }
        __syncthreads();
    }

    // epilogue: reduce l across the 16 lanes sharing each row, then normalize
#pragma unroll
    for (int r = 0; r < 4; r++) {
        float l = l_i[r];
#pragma unroll
        for (int off = 1; off < 16; off <<= 1) l += __shfl_xor(l, off);
        float inv = 1.0f / l;
        int qrow = q0 + (wave << 4) + (quad << 2) + r;
        size_t base = ((size_t)(b * S_LEN + qrow)) * HID + ((size_t)(bh & 31) << 7);
#pragma unroll
        for (int n = 0; n < 8; n++)
            ctx[base + (n << 4) + l16] = f2bf(o[n][r] * inv);
    }
}

extern "C" void kernel_launch(void* const* d_in, const int* in_sizes, int n_in,
                              void* d_out, int out_size, void* d_ws, size_t ws_size,
                              hipStream_t stream) {
    const float* x       = (const float*)d_in[0];
    const float* mask    = (const float*)d_in[1];
    const float* norm_w  = (const float*)d_in[2];
    const float* norm_b  = (const float*)d_in[3];
    const float* qkv_w   = (const float*)d_in[4];
    const float* qkv_b   = (const float*)d_in[5];
    const float* attn_ow = (const float*)d_in[6];
    float* out = (float*)d_out;

    char* ws = (char*)d_ws;
    size_t off = 0;
    auto alloc = [&](size_t bytes) {
        char* p = ws + off;
        off += (bytes + 255) & ~(size_t)255;
        return p;
    };
    unsigned short* inp_norm = (unsigned short*)alloc((size_t)2048 * HID * 2);
    unsigned short* qkv_wt   = (unsigned short*)alloc((size_t)3 * HID * HID * 2);
    unsigned short* ow_t     = (unsigned short*)alloc((size_t)HID * HID * 2);
    unsigned short* qb       = (unsigned short*)alloc((size_t)64 * S_LEN * HDIM * 2);
    unsigned short* kb       = (unsigned short*)alloc((size_t)64 * S_LEN * HDIM * 2);
    unsigned short* vt       = (unsigned short*)alloc((size_t)64 * S_LEN * HDIM * 2);
    unsigned short* ctx      = (unsigned short*)alloc((size_t)2048 * HID * 2);

    ln_kernel<<<2048, 256, 0, stream>>>(x, norm_w, norm_b, inp_norm);
    transconv<<<dim3(3 * HID / 128, HID / 64), 256, 0, stream>>>(qkv_w, qkv_wt, HID, 3 * HID);
    transconv<<<dim3(HID / 128, HID / 64), 256, 0, stream>>>(attn_ow, ow_t, HID, HID);
    gemm_qkv384<<<256, 512, 0, stream>>>(inp_norm, qkv_wt, qkv_b, qb, kb, vt);
    attn_kernel<<<dim3(16, 64), 256, 0, stream>>>(qb, kb, vt, mask, ctx);
    gemm_proj32<<<256, 512, 0, stream>>>(ctx, ow_t, out);
}